// Round 5
// baseline (690.851 us; speedup 1.0000x reference)
//
#include <hip/hip_runtime.h>
#include <math.h>

// Problem constants (fixed by the reference)
constexpr int BSZ = 2;
constexpr int SEQ = 2048;
constexpr int NE  = 2048;   // n_embd
constexpr int NH  = 16;
constexpr int HD  = 128;    // head_dim
constexpr int MROWS = BSZ * SEQ;  // 4096

typedef __bf16 bf16x8 __attribute__((ext_vector_type(8)));
typedef float  f32x4  __attribute__((ext_vector_type(4)));

// ---------------------------------------------------------------------------
// bf16 helpers
// ---------------------------------------------------------------------------
__device__ __forceinline__ unsigned short f2bf(float f) {
    union { float f; unsigned u; } v; v.f = f;
    unsigned r = v.u + 0x7fffu + ((v.u >> 16) & 1u);   // round-to-nearest-even
    return (unsigned short)(r >> 16);
}
__device__ __forceinline__ float bf2f(unsigned short s) {
    union { unsigned u; float f; } v; v.u = ((unsigned)s) << 16; return v.f;
}

// async global->LDS, 16 B per lane; lds ptr must be wave-uniform
__device__ __forceinline__ void load_lds16(const void* g, void* l) {
    __builtin_amdgcn_global_load_lds(
        (const __attribute__((address_space(1))) unsigned int*)g,
        (__attribute__((address_space(3))) unsigned int*)l, 16, 0, 0);
}

// ---------------------------------------------------------------------------
// x fp32 -> bf16 cast
// ---------------------------------------------------------------------------
__global__ __launch_bounds__(256) void cast_f32_bf16(const float* __restrict__ in,
                                                     ushort* __restrict__ out, int n)
{
    int i = (blockIdx.x * 256 + threadIdx.x) * 4;
    if (i >= n) return;
    float4 v = *(const float4*)(in + i);
    ushort4 o;
    o.x = f2bf(v.x); o.y = f2bf(v.y); o.z = f2bf(v.z); o.w = f2bf(v.w);
    *(ushort4*)(out + i) = o;
}

// ---------------------------------------------------------------------------
// Weight transpose + cast: W[K][N] fp32 -> Wt[N][K] bf16. blockIdx.z picks matrix.
// ---------------------------------------------------------------------------
__global__ __launch_bounds__(256) void transpose_cast(const float* __restrict__ w0,
                                                      const float* __restrict__ w1,
                                                      const float* __restrict__ w2,
                                                      const float* __restrict__ w3,
                                                      ushort* __restrict__ o0,
                                                      ushort* __restrict__ o1,
                                                      ushort* __restrict__ o2,
                                                      ushort* __restrict__ o3)
{
    const float* S; ushort* D;
    switch (blockIdx.z) {
        case 0: S = w0; D = o0; break;
        case 1: S = w1; D = o1; break;
        case 2: S = w2; D = o2; break;
        default: S = w3; D = o3; break;
    }
    __shared__ float t[32][33];
    const int tx = threadIdx.x, ty = threadIdx.y;
    const int x0 = blockIdx.x * 32, y0 = blockIdx.y * 32;
#pragma unroll
    for (int i = 0; i < 4; ++i)
        t[ty + i * 8][tx] = S[(size_t)(y0 + ty + i * 8) * NE + x0 + tx];
    __syncthreads();
#pragma unroll
    for (int i = 0; i < 4; ++i)
        D[(size_t)(x0 + ty + i * 8) * NE + y0 + tx] = f2bf(t[tx][ty + i * 8]);
}

// ---------------------------------------------------------------------------
// Fused QKV GEMM: C = xb[4096,2048] * W[6144,2048]^T (W = wqT|wkT|wvT stacked).
// 128x128 tile, BK=32, m97 structure. Epilogue by n-range:
//   mat 0 -> Qb row-major bf16, mat 1 -> Kb row-major bf16,
//   mat 2 -> Vt[b][h][d][s] bf16 (per-head transposed V for flash's B-frags).
// ---------------------------------------------------------------------------
__global__ __launch_bounds__(256) void gemm_qkv(const ushort* __restrict__ A,
                                                const ushort* __restrict__ W,
                                                ushort* __restrict__ Qb,
                                                ushort* __restrict__ Kb,
                                                ushort* __restrict__ Vt)
{
    __shared__ ushort Al[128 * 32];
    __shared__ ushort Bl[128 * 32];

    const int tid  = threadIdx.x;
    const int w    = tid >> 6;
    const int lane = tid & 63;
    const int quad = lane >> 4;
    const int r    = lane & 15;
    const int wm   = w & 1;
    const int wn   = w >> 1;
    const int m0 = blockIdx.y * 128;
    const int n0 = blockIdx.x * 128;      // 0..6143 (global row in stacked W)
    const int K  = NE;

    const int arow0 = tid >> 2;           const int akp = (tid & 3) * 8;
    const int arow1 = (256 + tid) >> 2;

    f32x4 acc[4][4] = {};

    for (int k0 = 0; k0 < K; k0 += 32) {
        load_lds16(A + (size_t)(m0 + arow0) * K + k0 + akp, &Al[(size_t)w * 512]);
        load_lds16(A + (size_t)(m0 + arow1) * K + k0 + akp, &Al[(size_t)(4 + w) * 512]);
        load_lds16(W + (size_t)(n0 + arow0) * K + k0 + akp, &Bl[(size_t)w * 512]);
        load_lds16(W + (size_t)(n0 + arow1) * K + k0 + akp, &Bl[(size_t)(4 + w) * 512]);
        __syncthreads();

        bf16x8 af[4], bfr[4];
#pragma unroll
        for (int it = 0; it < 4; ++it)
            af[it] = *(const bf16x8*)&Al[(wm * 64 + it * 16 + r) * 32 + quad * 8];
#pragma unroll
        for (int jt = 0; jt < 4; ++jt)
            bfr[jt] = *(const bf16x8*)&Bl[(wn * 64 + jt * 16 + r) * 32 + quad * 8];
#pragma unroll
        for (int it = 0; it < 4; ++it)
#pragma unroll
            for (int jt = 0; jt < 4; ++jt)
                acc[it][jt] = __builtin_amdgcn_mfma_f32_16x16x32_bf16(
                    af[it], bfr[jt], acc[it][jt], 0, 0, 0);
        __syncthreads();
    }

    const int mat  = n0 >> 11;        // 0=Q,1=K,2=V
    const int ncol = n0 & 2047;
    if (mat < 2) {
        ushort* C = mat ? Kb : Qb;
#pragma unroll
        for (int it = 0; it < 4; ++it) {
            const int row = m0 + wm * 64 + it * 16 + quad * 4;
#pragma unroll
            for (int jt = 0; jt < 4; ++jt) {
                const int col = ncol + wn * 64 + jt * 16 + r;
#pragma unroll
                for (int reg = 0; reg < 4; ++reg)
                    C[(size_t)(row + reg) * NE + col] = f2bf(acc[it][jt][reg]);
            }
        }
    } else {
#pragma unroll
        for (int it = 0; it < 4; ++it) {
            const int row = m0 + wm * 64 + it * 16 + quad * 4;   // 4-aligned
            const int bb = row >> 11;
            const int s  = row & 2047;
#pragma unroll
            for (int jt = 0; jt < 4; ++jt) {
                const int col = ncol + wn * 64 + jt * 16 + r;
                const int hh = col >> 7;
                const int d  = col & 127;
                ushort4 pk;
                pk.x = f2bf(acc[it][jt][0]); pk.y = f2bf(acc[it][jt][1]);
                pk.z = f2bf(acc[it][jt][2]); pk.w = f2bf(acc[it][jt][3]);
                *(ushort4*)&Vt[((size_t)((bb * NH + hh) * HD + d)) * SEQ + s] = pk;
            }
        }
    }
}

// ---------------------------------------------------------------------------
// Output GEMM: out[4096,2048] f32 = Yb[4096,2048] bf16 * woT[2048,2048]^T
// ---------------------------------------------------------------------------
__global__ __launch_bounds__(256) void gemm_out(const ushort* __restrict__ A,
                                                const ushort* __restrict__ Bt,
                                                float* __restrict__ C)
{
    __shared__ ushort Al[128 * 32];
    __shared__ ushort Bl[128 * 32];

    const int tid  = threadIdx.x;
    const int w    = tid >> 6;
    const int lane = tid & 63;
    const int quad = lane >> 4;
    const int r    = lane & 15;
    const int wm   = w & 1;
    const int wn   = w >> 1;
    const int m0 = blockIdx.y * 128;
    const int n0 = blockIdx.x * 128;
    const int K  = NE;

    const int arow0 = tid >> 2;           const int akp = (tid & 3) * 8;
    const int arow1 = (256 + tid) >> 2;

    f32x4 acc[4][4] = {};

    for (int k0 = 0; k0 < K; k0 += 32) {
        load_lds16(A  + (size_t)(m0 + arow0) * K + k0 + akp, &Al[(size_t)w * 512]);
        load_lds16(A  + (size_t)(m0 + arow1) * K + k0 + akp, &Al[(size_t)(4 + w) * 512]);
        load_lds16(Bt + (size_t)(n0 + arow0) * K + k0 + akp, &Bl[(size_t)w * 512]);
        load_lds16(Bt + (size_t)(n0 + arow1) * K + k0 + akp, &Bl[(size_t)(4 + w) * 512]);
        __syncthreads();

        bf16x8 af[4], bfr[4];
#pragma unroll
        for (int it = 0; it < 4; ++it)
            af[it] = *(const bf16x8*)&Al[(wm * 64 + it * 16 + r) * 32 + quad * 8];
#pragma unroll
        for (int jt = 0; jt < 4; ++jt)
            bfr[jt] = *(const bf16x8*)&Bl[(wn * 64 + jt * 16 + r) * 32 + quad * 8];
#pragma unroll
        for (int it = 0; it < 4; ++it)
#pragma unroll
            for (int jt = 0; jt < 4; ++jt)
                acc[it][jt] = __builtin_amdgcn_mfma_f32_16x16x32_bf16(
                    af[it], bfr[jt], acc[it][jt], 0, 0, 0);
        __syncthreads();
    }

#pragma unroll
    for (int it = 0; it < 4; ++it) {
        const int row = m0 + wm * 64 + it * 16 + quad * 4;
#pragma unroll
        for (int jt = 0; jt < 4; ++jt) {
            const int col = n0 + wn * 64 + jt * 16 + r;
#pragma unroll
            for (int reg = 0; reg < 4; ++reg)
                C[(size_t)(row + reg) * NE + col] = acc[it][jt][reg];
        }
    }
}

// ---------------------------------------------------------------------------
// RoPE in-place on bf16 Q and K.
// ---------------------------------------------------------------------------
__global__ __launch_bounds__(256) void rope_bf16(ushort* __restrict__ Q,
                                                 ushort* __restrict__ K)
{
    const size_t npairs = (size_t)MROWS * NE / 2;
    size_t idx = (size_t)blockIdx.x * blockDim.x + threadIdx.x;
    if (idx >= npairs) return;
    ushort* P = blockIdx.y ? K : Q;

    const int r = (int)(idx / (NE / 2));
    const int c = (int)(idx % (NE / 2));
    const int s = r % SEQ;
    const int i = c & 63;

    const float inv_freq = powf(10000.0f, -((float)i) / 64.0f);
    const float f = (float)s * inv_freq;
    float sn, cs;
    sincosf(f, &sn, &cs);

    unsigned* p = (unsigned*)(P + (size_t)r * NE) + c;
    unsigned v = *p;
    const float x1 = bf2f((unsigned short)(v & 0xffffu));
    const float x2 = bf2f((unsigned short)(v >> 16));
    const float y1 = x1 * cs - x2 * sn;
    const float y2 = x1 * sn + x2 * cs;
    *p = (unsigned)f2bf(y1) | ((unsigned)f2bf(y2) << 16);
}

// ---------------------------------------------------------------------------
// MFMA flash attention v2. Block = 64 q-rows of one (b,h); 4 waves, wave w
// owns q strip [w*16, w*16+16). KV tiles of 64. Causal, online softmax.
// Changes vs v1:
//  - Q A-frags loaded directly global->VGPR (Qs LDS dropped): 43.5 KB LDS
//    -> 3 blocks/CU (__launch_bounds__(256,3)).
//  - K/V staging software-pipelined: tile t+1 prefetched into registers
//    during compute of tile t. 2 barriers/step.
//  - P LDS round-trip is wave-private (rows [16w,16w+16)) -> no barrier.
//  - Ps stride 68 (full 32-bank write spread; was 16 banks at stride 72).
//  - l_i kept as per-lane partial; single 16-lane reduce in epilogue.
// Y aliases Q safely (block writes exactly the Q slice it alone reads).
// ---------------------------------------------------------------------------
__global__ __launch_bounds__(256, 3) void flash_attn(const ushort* __restrict__ Qg,
                                                     const ushort* __restrict__ Kg,
                                                     const ushort* __restrict__ Vtg,
                                                     ushort* __restrict__ Yg)
{
    const int qt = (int)gridDim.x - 1 - (int)blockIdx.x;  // big blocks first
    const int bh = blockIdx.y;
    const int b = bh >> 4, h = bh & 15;
    const int tid  = threadIdx.x;
    const int w    = tid >> 6;
    const int lane = tid & 63;
    const int quad = lane >> 4;
    const int r    = lane & 15;

    __shared__ ushort Ks[64][136];    // 17408 B
    __shared__ ushort Vts[128][72];   // 18432 B
    __shared__ ushort Ps[64][68];     //  8704 B   (total 43.5 KB)

    const int q0 = qt * 64;
    const size_t qkbase = (size_t)b * SEQ * NE + (size_t)h * HD;
    const size_t vbase  = (size_t)(bh * HD) * SEQ;
    const float scale = 0.088388347648318447f;  // 1/sqrt(128)

    // ---- Q A-frags direct from global (wave-private 16 rows) ----
    bf16x8 aq[4];
    {
        const ushort* qrow = Qg + qkbase + (size_t)(q0 + w * 16 + r) * NE;
#pragma unroll
        for (int kc = 0; kc < 4; ++kc)
            aq[kc] = *(const bf16x8*)(qrow + kc * 32 + quad * 8);
    }

    // staging geometry
    const int krow = tid >> 4;            // 0..15
    const int kch  = (tid & 15) * 8;      // 0..120
    const int vd   = tid >> 3;            // 0..31
    const int vch  = (tid & 7) * 8;       // 0..56

    const ushort* Kbase = Kg + qkbase;
    const ushort* Vbase = Vtg + vbase;

    uint4 kreg[4], vreg[4];
    {
        const int j0 = 0;
#pragma unroll
        for (int i = 0; i < 4; ++i)
            kreg[i] = *(const uint4*)(Kbase + (size_t)(j0 + i * 16 + krow) * NE + kch);
#pragma unroll
        for (int i = 0; i < 4; ++i)
            vreg[i] = *(const uint4*)(Vbase + (size_t)(i * 32 + vd) * SEQ + j0 + vch);
    }

    float m_i[4], l_i[4];
    f32x4 acc_o[8];
#pragma unroll
    for (int reg = 0; reg < 4; ++reg) { m_i[reg] = -INFINITY; l_i[reg] = 0.f; }
#pragma unroll
    for (int dt = 0; dt < 8; ++dt) acc_o[dt] = f32x4{0.f, 0.f, 0.f, 0.f};

    for (int t = 0; t <= qt; ++t) {
        // ---- store prefetched K/V tile to LDS ----
        if (t) __syncthreads();           // prior step done reading Ks/Vts
#pragma unroll
        for (int i = 0; i < 4; ++i)
            *(uint4*)&Ks[i * 16 + krow][kch] = kreg[i];
#pragma unroll
        for (int i = 0; i < 4; ++i)
            *(uint4*)&Vts[i * 32 + vd][vch] = vreg[i];
        __syncthreads();

        // ---- prefetch tile t+1 (latency hidden behind compute below) ----
        if (t < qt) {
            const int j0 = (t + 1) * 64;
#pragma unroll
            for (int i = 0; i < 4; ++i)
                kreg[i] = *(const uint4*)(Kbase + (size_t)(j0 + i * 16 + krow) * NE + kch);
#pragma unroll
            for (int i = 0; i < 4; ++i)
                vreg[i] = *(const uint4*)(Vbase + (size_t)(i * 32 + vd) * SEQ + j0 + vch);
        }

        // ---- S = Q K^T (wave strip: 16q x 64kv) ----
        f32x4 sa[4];
#pragma unroll
        for (int jt = 0; jt < 4; ++jt) {
            f32x4 acc = {0.f, 0.f, 0.f, 0.f};
#pragma unroll
            for (int kc = 0; kc < 4; ++kc) {
                bf16x8 bk = *(const bf16x8*)&Ks[jt * 16 + r][kc * 32 + quad * 8];
                acc = __builtin_amdgcn_mfma_f32_16x16x32_bf16(aq[kc], bk, acc, 0, 0, 0);
            }
            sa[jt] = acc;
        }

        // ---- scale + causal mask (diag tile only) ----
        if (t == qt) {
#pragma unroll
            for (int jt = 0; jt < 4; ++jt)
#pragma unroll
                for (int reg = 0; reg < 4; ++reg)
                    sa[jt][reg] = (jt * 16 + r > w * 16 + quad * 4 + reg)
                                  ? -INFINITY : sa[jt][reg] * scale;
        } else {
#pragma unroll
            for (int jt = 0; jt < 4; ++jt)
#pragma unroll
                for (int reg = 0; reg < 4; ++reg)
                    sa[jt][reg] *= scale;
        }

        // ---- online softmax (row = quad*4+reg; max across 16 col lanes) ----
        float rmax[4], alpha[4];
#pragma unroll
        for (int reg = 0; reg < 4; ++reg)
            rmax[reg] = fmaxf(fmaxf(sa[0][reg], sa[1][reg]),
                              fmaxf(sa[2][reg], sa[3][reg]));
#pragma unroll
        for (int off = 1; off < 16; off <<= 1)
#pragma unroll
            for (int reg = 0; reg < 4; ++reg)
                rmax[reg] = fmaxf(rmax[reg], __shfl_xor(rmax[reg], off, 64));

#pragma unroll
        for (int reg = 0; reg < 4; ++reg) {
            const float mnew = fmaxf(m_i[reg], rmax[reg]);
            alpha[reg] = __expf(m_i[reg] - mnew);
            m_i[reg] = mnew;
        }
        float rsum[4] = {0.f, 0.f, 0.f, 0.f};
#pragma unroll
        for (int jt = 0; jt < 4; ++jt)
#pragma unroll
            for (int reg = 0; reg < 4; ++reg) {
                const float p = __expf(sa[jt][reg] - m_i[reg]);
                sa[jt][reg] = p;
                rsum[reg] += p;
            }
        // l stays a per-lane partial (reduced once in the epilogue)
#pragma unroll
        for (int reg = 0; reg < 4; ++reg)
            l_i[reg] = l_i[reg] * alpha[reg] + rsum[reg];

        // ---- P -> LDS (wave-private rows; no barrier needed) ----
#pragma unroll
        for (int jt = 0; jt < 4; ++jt)
#pragma unroll
            for (int reg = 0; reg < 4; ++reg)
                Ps[w * 16 + quad * 4 + reg][jt * 16 + r] = f2bf(sa[jt][reg]);

        // ---- O = O*alpha + P V ----
#pragma unroll
        for (int dt = 0; dt < 8; ++dt)
#pragma unroll
            for (int reg = 0; reg < 4; ++reg)
                acc_o[dt][reg] *= alpha[reg];

        bf16x8 ap[2];
#pragma unroll
        for (int kc = 0; kc < 2; ++kc)
            ap[kc] = *(const bf16x8*)&Ps[w * 16 + r][kc * 32 + quad * 8];
#pragma unroll
        for (int dt = 0; dt < 8; ++dt)
#pragma unroll
            for (int kc = 0; kc < 2; ++kc) {
                bf16x8 bv = *(const bf16x8*)&Vts[dt * 16 + r][kc * 32 + quad * 8];
                acc_o[dt] = __builtin_amdgcn_mfma_f32_16x16x32_bf16(ap[kc], bv, acc_o[dt], 0, 0, 0);
            }
    }

    // ---- Epilogue: reduce l across the 16 col lanes, O /= l, write bf16 ----
#pragma unroll
    for (int off = 1; off < 16; off <<= 1)
#pragma unroll
        for (int reg = 0; reg < 4; ++reg)
            l_i[reg] += __shfl_xor(l_i[reg], off, 64);

#pragma unroll
    for (int reg = 0; reg < 4; ++reg) {
        const float inv = 1.0f / l_i[reg];
        const size_t rowbase = qkbase + (size_t)(q0 + w * 16 + quad * 4 + reg) * NE;
#pragma unroll
        for (int dt = 0; dt < 8; ++dt)
            Yg[rowbase + dt * 16 + r] = f2bf(acc_o[dt][reg] * inv);
    }
}

// ---------------------------------------------------------------------------
extern "C" void kernel_launch(void* const* d_in, const int* in_sizes, int n_in,
                              void* d_out, int out_size, void* d_ws, size_t ws_size,
                              hipStream_t stream)
{
    const float* x  = (const float*)d_in[0];
    const float* wq = (const float*)d_in[1];
    const float* wk = (const float*)d_in[2];
    const float* wv = (const float*)d_in[3];
    const float* wo = (const float*)d_in[4];
    float* out = (float*)d_out;

    // ws (bf16 elems): xb | wqT wkT wvT woT | Qb | Kb | Vt   = 96 MiB
    ushort* ws = (ushort*)d_ws;
    const size_t MAT  = (size_t)MROWS * NE;   // 8M
    const size_t WMAT = (size_t)NE * NE;      // 4M
    ushort* xb  = ws;
    ushort* wqT = xb + MAT;
    ushort* wkT = wqT + WMAT;
    ushort* wvT = wkT + WMAT;
    ushort* woT = wvT + WMAT;
    ushort* Qb  = woT + WMAT;
    ushort* Kb  = Qb + MAT;
    ushort* Vt  = Kb + MAT;
    ushort* Yb  = Qb;   // alias, safe (see flash_attn)

    cast_f32_bf16<<<(unsigned)(MAT / 4 / 256), 256, 0, stream>>>(x, xb, (int)MAT);
    transpose_cast<<<dim3(64, 64, 4), dim3(32, 8), 0, stream>>>(
        wq, wk, wv, wo, wqT, wkT, wvT, woT);

    // Fused QKV: W = wqT|wkT|wvT stacked (contiguous) = [6144][2048]
    gemm_qkv<<<dim3(48, 32), 256, 0, stream>>>(xb, wqT, Qb, Kb, Vt);

    const size_t npairs = (size_t)MROWS * NE / 2;
    rope_bf16<<<dim3((unsigned)(npairs / 256), 2), 256, 0, stream>>>(Qb, Kb);

    flash_attn<<<dim3(SEQ / 64, BSZ * NH), 256, 0, stream>>>(Qb, Kb, Vt, Yb);

    gemm_out<<<dim3(16, 32), 256, 0, stream>>>(Yb, woT, out);
}